// Round 1
// baseline (160.377 us; speedup 1.0000x reference)
//
#include <hip/hip_runtime.h>
#include <math.h>

#define D 196
#define NCH 64
#define NH 8
#define DHD 64
#define INNER 512
#define MLP 784
#define SEQ 65

__device__ __forceinline__ float bsum(float v, float* red) {   // 256-thread blocks
    for (int off = 32; off > 0; off >>= 1) v += __shfl_down(v, off, 64);
    int lane = threadIdx.x & 63, wid = threadIdx.x >> 6;
    if (lane == 0) red[wid] = v;
    __syncthreads();
    float s = red[0] + red[1] + red[2] + red[3];
    __syncthreads();
    return s;
}

__device__ __forceinline__ float bsum8(float v, float* red) {  // 512-thread blocks
    for (int off = 32; off > 0; off >>= 1) v += __shfl_down(v, off, 64);
    int lane = threadIdx.x & 63, wid = threadIdx.x >> 6;
    if (lane == 0) red[wid] = v;
    __syncthreads();
    float s = red[0] + red[1] + red[2] + red[3] + red[4] + red[5] + red[6] + red[7];
    __syncthreads();
    return s;
}

// ===== K1: conv+mean (blocks 0..63) | LN1+QKV splitK4 x colpair (64..843) =====
__global__ void __launch_bounds__(256) k1(const float* __restrict__ x_pe,
        const float* __restrict__ conv_k, const float* __restrict__ bn_g,
        const float* __restrict__ bn_b, const float* __restrict__ bn_rm,
        const float* __restrict__ bn_rv, const float* __restrict__ x,
        const float* __restrict__ ln1_g, const float* __restrict__ ln1_b,
        const float* __restrict__ w_qkv,
        float* __restrict__ a, float* __restrict__ b1, float* __restrict__ qkv) {
    __shared__ float red[4];
    __shared__ float h[D];
    __shared__ float ps[512];
    int b = blockIdx.x, t = threadIdx.x;
    if (b < NCH) {
        const float* row = x_pe + b * D;
        float val = 0.f;
        if (t < D) {
            float km0 = conv_k[3], km1 = conv_k[4], km2 = conv_k[5];
            float inv = rsqrtf(bn_rv[0] + 1e-5f);
            float l = (t > 0) ? row[t - 1] : 0.f;
            float m = row[t];
            float r = (t < D - 1) ? row[t + 1] : 0.f;
            float conv = km0 * l + km1 * m + km2 * r;
            float bn = (conv - bn_rm[0]) * inv * bn_g[0] + bn_b[0];
            val = fmaxf(bn, 0.f);
            a[b * D + t] = val;
        }
        float tot = bsum(val, red);
        if (t == 0) b1[b] = tot * (1.f / (float)D);
    } else {
        int qb = b - NCH;          // 0..779
        int n = qb / 12, cg = qb % 12;
        const float* row = x + n * D;
        float v = (t < D) ? row[t] : 0.f;
        float mean = bsum(v, red) * (1.f / (float)D);
        float d = (t < D) ? (v - mean) : 0.f;
        float var = bsum(d * d, red) * (1.f / (float)D);
        float rinv = rsqrtf(var + 1e-5f);
        if (t < D) h[t] = d * rinv * ln1_g[t] + ln1_b[t];
        __syncthreads();
        int qq = t >> 6, lt = t & 63;        // qq: K quarter, lt: col pair
        int c0 = cg * 128 + lt * 2;
        const float* wp = w_qkv + (qq * 49) * 1536 + c0;
        const float* hp = h + qq * 49;
        float a0 = 0.f, a1 = 0.f;
#pragma unroll
        for (int i = 0; i < 49; i++) {
            float2 w2 = *(const float2*)(wp + i * 1536);
            float hv = hp[i];
            a0 += hv * w2.x;
            a1 += hv * w2.y;
        }
        ps[qq * 128 + lt * 2] = a0;
        ps[qq * 128 + lt * 2 + 1] = a1;
        __syncthreads();
        if (t < 64) {
            float s0 = ps[t * 2] + ps[128 + t * 2] + ps[256 + t * 2] + ps[384 + t * 2];
            float s1 = ps[t * 2 + 1] + ps[129 + t * 2] + ps[257 + t * 2] + ps[385 + t * 2];
            float2 o2 = make_float2(s0, s1);
            *(float2*)(qkv + n * 1536 + cg * 128 + t * 2) = o2;
        }
    }
}

// ===== K2: fused attention + out-proj + gate + x_att + LN2 + FF1 + FF2 + resid
//       grid = 65 blocks (one per row), 512 threads =====
__global__ void __launch_bounds__(512) k2(const float* __restrict__ b1,
        const float* __restrict__ fc_w1, const float* __restrict__ fc_w2,
        const float* __restrict__ qkv, const float* __restrict__ w_out,
        const float* __restrict__ b_out, const float* __restrict__ x,
        const float* __restrict__ a, const float* __restrict__ tokens,
        const float* __restrict__ ln2_g, const float* __restrict__ ln2_b,
        const float* __restrict__ ff_w1, const float* __restrict__ ff_b1,
        const float* __restrict__ ff_w2, const float* __restrict__ ff_b2,
        float* __restrict__ out) {
    __shared__ float red[8];
    __shared__ float sq[512];      // q of row n (8 heads x 64)
    __shared__ float pp[8 * 80];   // attn probs per head
    __shared__ float so[512];      // attn out (8 x 64)
    __shared__ float ps[784];      // splitK partials (out-proj / FF2)
    __shared__ float x2row[D];     // post-attn residual row (incl. x_att)
    __shared__ float h2[D];        // LN2 output
    __shared__ float tbs[MLP];     // FF1 + GELU output
    __shared__ float sb1[NCH];
    __shared__ float sb2[NCH];
    __shared__ float hid[12];
    __shared__ float cgate;

    int n = blockIdx.x, t = threadIdx.x;

    // issue q load early; gate (depends only on b1) runs first
    sq[t] = qkv[n * 1536 + t];
    if (t < NCH) sb1[t] = b1[t];
    __syncthreads();
    if (t < NCH) {
        float v = sb1[t];
        float mx = -1e30f, mn = 1e30f;
        int cle = 0, rank = 0;
        for (int j = 0; j < NCH; j++) {
            float w = sb1[j];
            mx = fmaxf(mx, w);
            mn = fminf(mn, w);
            if (w <= 0.f) cle++;
            if (w < v || (w == v && j < t)) rank++;
        }
        int middle;
        if (mx < 0.f || mn > 0.f) middle = 32;
        else if (mx <= 0.f) middle = 0;
        else middle = cle;
        float b2;
        if (rank < middle) {
            float ls = (float)middle;
            b2 = v - 1.f / (1.f + powf(ls, v));
        } else {
            float le = (float)(NCH - middle);
            b2 = v + 1.f / (1.f + powf(le, -v));
        }
        sb2[t] = b2;
    }
    __syncthreads();
    if (t < 12) {
        float s = 0.f;
        for (int j = 0; j < NCH; j++) s += sb2[j] * fc_w1[j * 12 + t];
        hid[t] = fmaxf(s, 0.f);
    }
    __syncthreads();
    if (t == 0 && n < NCH) {
        float s = 0.f;
        for (int k = 0; k < 12; k++) s += hid[k] * fc_w2[k * NCH + n];
        cgate = 1.f / (1.f + expf(-s));
    }
    __syncthreads();

    // ---- attention: 8 waves = 8 heads ----
    const float scale = 0.125f;
    int w = t >> 6, L = t & 63;   // head, lane
    const float4* kr = (const float4*)(qkv + L * 1536 + INNER + w * DHD);
    const float4* q4 = (const float4*)(sq + w * DHD);
    float s = 0.f;
#pragma unroll
    for (int i = 0; i < 16; i++) {
        float4 kv = kr[i];
        float4 qv = q4[i];
        s += qv.x * kv.x + qv.y * kv.y + qv.z * kv.z + qv.w * kv.w;
    }
    float sL = s * scale;
    float t64 = sq[w * DHD + L] * qkv[64 * 1536 + INNER + w * DHD + L];
#pragma unroll
    for (int off = 1; off < 64; off <<= 1) t64 += __shfl_xor(t64, off, 64);
    float s64 = t64 * scale;
    float mx = sL;
#pragma unroll
    for (int off = 1; off < 64; off <<= 1) mx = fmaxf(mx, __shfl_xor(mx, off, 64));
    mx = fmaxf(mx, s64);
    float e = expf(sL - mx);
    float e64 = expf(s64 - mx);
    float esum = e;
#pragma unroll
    for (int off = 1; off < 64; off <<= 1) esum += __shfl_xor(esum, off, 64);
    esum += e64;
    float rs = 1.f / esum;
    pp[w * 80 + L] = e;
    if (L == 0) pp[w * 80 + 64] = e64;
    __syncthreads();
    float acc = 0.f;
#pragma unroll 13
    for (int m = 0; m < SEQ; m++)
        acc += pp[w * 80 + m] * qkv[m * 1536 + 2 * INNER + w * DHD + L];
    so[w * DHD + L] = acc * rs;
    __syncthreads();

    // ---- out-projection: 98 col-pairs x 4 K-quarters ----
    if (t < 392) {
        int qq = t / 98, p = t - qq * 98;
        const float* wp = w_out + (qq * 128) * D + 2 * p;
        const float* op = so + qq * 128;
        float a0 = 0.f, a1 = 0.f;
#pragma unroll 16
        for (int i = 0; i < 128; i++) {
            float2 w2 = *(const float2*)(wp + i * D);
            float ov = op[i];
            a0 += ov * w2.x;
            a1 += ov * w2.y;
        }
        ps[qq * 196 + 2 * p] = a0;
        ps[qq * 196 + 2 * p + 1] = a1;
    }
    __syncthreads();
    if (t < 98) {
        float s0 = ps[2 * t] + ps[196 + 2 * t] + ps[392 + 2 * t] + ps[588 + 2 * t];
        float s1 = ps[2 * t + 1] + ps[197 + 2 * t] + ps[393 + 2 * t] + ps[589 + 2 * t];
        float2 xr = *(const float2*)(x + n * D + 2 * t);
        float2 br = *(const float2*)(b_out + 2 * t);
        x2row[2 * t] = s0 + xr.x + br.x;
        x2row[2 * t + 1] = s1 + xr.y + br.y;
    }
    __syncthreads();

    // ---- add x_att into residual row ----
    if (t < D) {
        float att = (n < NCH) ? a[n * D + t] * cgate : tokens[t];
        x2row[t] += att;
    }
    __syncthreads();

    // ---- LN2 ----
    float v = (t < D) ? x2row[t] : 0.f;
    float mean = bsum8(v, red) * (1.f / (float)D);
    float d = (t < D) ? (v - mean) : 0.f;
    float var = bsum8(d * d, red) * (1.f / (float)D);
    float rinv = rsqrtf(var + 1e-5f);
    if (t < D) h2[t] = d * rinv * ln2_g[t] + ln2_b[t];
    __syncthreads();

    // ---- FF1 + GELU: 392 threads x 2 cols, full K=196 ----
    if (t < 392) {
        int c0 = 2 * t;
        const float* wp = ff_w1 + c0;
        float a0 = 0.f, a1 = 0.f;
#pragma unroll 4
        for (int i = 0; i < D; i++) {
            float2 w2 = *(const float2*)(wp + i * MLP);
            float hv = h2[i];
            a0 += hv * w2.x;
            a1 += hv * w2.y;
        }
        a0 += ff_b1[c0];
        a1 += ff_b1[c0 + 1];
        tbs[c0] = 0.5f * a0 * (1.f + erff(a0 * 0.70710678118f));
        tbs[c0 + 1] = 0.5f * a1 * (1.f + erff(a1 * 0.70710678118f));
    }
    __syncthreads();

    // ---- FF2 splitK4 x colpair + residual, direct store ----
    if (t < 392) {
        int qq = t / 98, p = t - qq * 98;
        const float* wp = ff_w2 + (qq * 196) * D + 2 * p;
        const float* sp = tbs + qq * 196;
        float a0 = 0.f, a1 = 0.f;
#pragma unroll 4
        for (int i = 0; i < 196; i++) {
            float2 w2 = *(const float2*)(wp + i * D);
            float sv = sp[i];
            a0 += sv * w2.x;
            a1 += sv * w2.y;
        }
        ps[qq * 196 + 2 * p] = a0;
        ps[qq * 196 + 2 * p + 1] = a1;
    }
    __syncthreads();
    if (t < 98) {
        float s0 = ps[2 * t] + ps[196 + 2 * t] + ps[392 + 2 * t] + ps[588 + 2 * t];
        float s1 = ps[2 * t + 1] + ps[197 + 2 * t] + ps[393 + 2 * t] + ps[589 + 2 * t];
        float2 br = *(const float2*)(ff_b2 + 2 * t);
        float2 o2 = make_float2(s0 + br.x + x2row[2 * t],
                                s1 + br.y + x2row[2 * t + 1]);
        *(float2*)(out + n * D + 2 * t) = o2;
    }
}

extern "C" void kernel_launch(void* const* d_in, const int* in_sizes, int n_in,
                              void* d_out, int out_size, void* d_ws, size_t ws_size,
                              hipStream_t stream) {
    const float* x      = (const float*)d_in[0];
    const float* tokens = (const float*)d_in[1];
    const float* x_pe   = (const float*)d_in[2];
    const float* conv_k = (const float*)d_in[3];
    const float* bn_g   = (const float*)d_in[4];
    const float* bn_b   = (const float*)d_in[5];
    const float* bn_rm  = (const float*)d_in[6];
    const float* bn_rv  = (const float*)d_in[7];
    const float* fc_w1  = (const float*)d_in[8];
    const float* fc_w2  = (const float*)d_in[9];
    const float* ln1_g  = (const float*)d_in[10];
    const float* ln1_b  = (const float*)d_in[11];
    const float* ln2_g  = (const float*)d_in[12];
    const float* ln2_b  = (const float*)d_in[13];
    const float* w_qkv  = (const float*)d_in[14];
    const float* w_out  = (const float*)d_in[15];
    const float* b_out  = (const float*)d_in[16];
    const float* ff_w1  = (const float*)d_in[17];
    const float* ff_b1  = (const float*)d_in[18];
    const float* ff_w2  = (const float*)d_in[19];
    const float* ff_b2  = (const float*)d_in[20];
    float* out = (float*)d_out;

    float* ws = (float*)d_ws;
    float* a    = ws;             // 12544
    float* b1   = ws + 12544;     // 64
    float* qkv  = ws + 12608;     // 99840

    k1<<<844, 256, 0, stream>>>(x_pe, conv_k, bn_g, bn_b, bn_rm, bn_rv,
                                x, ln1_g, ln1_b, w_qkv, a, b1, qkv);
    k2<<<SEQ, 512, 0, stream>>>(b1, fc_w1, fc_w2, qkv, w_out, b_out, x,
                                a, tokens, ln2_g, ln2_b,
                                ff_w1, ff_b1, ff_w2, ff_b2, out);
}

// Round 2
// 137.373 us; speedup vs baseline: 1.1675x; 1.1675x over previous
//
#include <hip/hip_runtime.h>
#include <math.h>

#define D 196
#define NCH 64
#define NH 8
#define DHD 64
#define INNER 512
#define MLP 784
#define SEQ 65

__device__ __forceinline__ float bsum(float v, float* red) {   // 256-thread blocks
    for (int off = 32; off > 0; off >>= 1) v += __shfl_down(v, off, 64);
    int lane = threadIdx.x & 63, wid = threadIdx.x >> 6;
    if (lane == 0) red[wid] = v;
    __syncthreads();
    float s = red[0] + red[1] + red[2] + red[3];
    __syncthreads();
    return s;
}

__device__ __forceinline__ float bsum8(float v, float* red) {  // 512-thread blocks
    for (int off = 32; off > 0; off >>= 1) v += __shfl_down(v, off, 64);
    int lane = threadIdx.x & 63, wid = threadIdx.x >> 6;
    if (lane == 0) red[wid] = v;
    __syncthreads();
    float s = red[0] + red[1] + red[2] + red[3] + red[4] + red[5] + red[6] + red[7];
    __syncthreads();
    return s;
}

// ===== K1: conv+mean (blocks 0..63) | LN1+QKV splitK4 x colpair (64..843) =====
__global__ void __launch_bounds__(256) k1(const float* __restrict__ x_pe,
        const float* __restrict__ conv_k, const float* __restrict__ bn_g,
        const float* __restrict__ bn_b, const float* __restrict__ bn_rm,
        const float* __restrict__ bn_rv, const float* __restrict__ x,
        const float* __restrict__ ln1_g, const float* __restrict__ ln1_b,
        const float* __restrict__ w_qkv,
        float* __restrict__ a, float* __restrict__ b1, float* __restrict__ qkv) {
    __shared__ float red[4];
    __shared__ float h[D];
    __shared__ float ps[512];
    int b = blockIdx.x, t = threadIdx.x;
    if (b < NCH) {
        const float* row = x_pe + b * D;
        float val = 0.f;
        if (t < D) {
            float km0 = conv_k[3], km1 = conv_k[4], km2 = conv_k[5];
            float inv = rsqrtf(bn_rv[0] + 1e-5f);
            float l = (t > 0) ? row[t - 1] : 0.f;
            float m = row[t];
            float r = (t < D - 1) ? row[t + 1] : 0.f;
            float conv = km0 * l + km1 * m + km2 * r;
            float bn = (conv - bn_rm[0]) * inv * bn_g[0] + bn_b[0];
            val = fmaxf(bn, 0.f);
            a[b * D + t] = val;
        }
        float tot = bsum(val, red);
        if (t == 0) b1[b] = tot * (1.f / (float)D);
    } else {
        int qb = b - NCH;          // 0..779
        int n = qb / 12, cg = qb % 12;
        const float* row = x + n * D;
        float v = (t < D) ? row[t] : 0.f;
        float mean = bsum(v, red) * (1.f / (float)D);
        float d = (t < D) ? (v - mean) : 0.f;
        float var = bsum(d * d, red) * (1.f / (float)D);
        float rinv = rsqrtf(var + 1e-5f);
        if (t < D) h[t] = d * rinv * ln1_g[t] + ln1_b[t];
        __syncthreads();
        int qq = t >> 6, lt = t & 63;        // qq: K quarter, lt: col pair
        int c0 = cg * 128 + lt * 2;
        const float* wp = w_qkv + (qq * 49) * 1536 + c0;
        const float* hp = h + qq * 49;
        float a0 = 0.f, a1 = 0.f;
#pragma unroll
        for (int i = 0; i < 49; i++) {
            float2 w2 = *(const float2*)(wp + i * 1536);
            float hv = hp[i];
            a0 += hv * w2.x;
            a1 += hv * w2.y;
        }
        ps[qq * 128 + lt * 2] = a0;
        ps[qq * 128 + lt * 2 + 1] = a1;
        __syncthreads();
        if (t < 64) {
            float s0 = ps[t * 2] + ps[128 + t * 2] + ps[256 + t * 2] + ps[384 + t * 2];
            float s1 = ps[t * 2 + 1] + ps[129 + t * 2] + ps[257 + t * 2] + ps[385 + t * 2];
            float2 o2 = make_float2(s0, s1);
            *(float2*)(qkv + n * 1536 + cg * 128 + t * 2) = o2;
        }
    }
}

// ===== K2: gate + attention + out-proj + x_att + LN2; writes h2 and
//       out = x2row + ff_b2.  grid = 65 blocks, 512 threads =====
__global__ void __launch_bounds__(512) k2(const float* __restrict__ b1,
        const float* __restrict__ fc_w1, const float* __restrict__ fc_w2,
        const float* __restrict__ qkv, const float* __restrict__ w_out,
        const float* __restrict__ b_out, const float* __restrict__ x,
        const float* __restrict__ a, const float* __restrict__ tokens,
        const float* __restrict__ ln2_g, const float* __restrict__ ln2_b,
        const float* __restrict__ ff_b2,
        float* __restrict__ h2g, float* __restrict__ out) {
    __shared__ float red[8];
    __shared__ float sq[512];      // q of row n (8 heads x 64)
    __shared__ float pp[8 * 80];   // attn probs per head
    __shared__ float so[512];      // attn out (8 x 64)
    __shared__ float ps[784];      // splitK partials (out-proj)
    __shared__ float x2row[D];     // post-attn residual row (incl. x_att)
    __shared__ float sb1[NCH];
    __shared__ float sb2[NCH];
    __shared__ float hid[12];
    __shared__ float cgate;

    int n = blockIdx.x, t = threadIdx.x;

    sq[t] = qkv[n * 1536 + t];
    if (t < NCH) sb1[t] = b1[t];
    __syncthreads();
    if (t < NCH) {
        float v = sb1[t];
        float mx = -1e30f, mn = 1e30f;
        int cle = 0, rank = 0;
        for (int j = 0; j < NCH; j++) {
            float w = sb1[j];
            mx = fmaxf(mx, w);
            mn = fminf(mn, w);
            if (w <= 0.f) cle++;
            if (w < v || (w == v && j < t)) rank++;
        }
        int middle;
        if (mx < 0.f || mn > 0.f) middle = 32;
        else if (mx <= 0.f) middle = 0;
        else middle = cle;
        float b2;
        if (rank < middle) {
            float ls = (float)middle;
            b2 = v - 1.f / (1.f + powf(ls, v));
        } else {
            float le = (float)(NCH - middle);
            b2 = v + 1.f / (1.f + powf(le, -v));
        }
        sb2[t] = b2;
    }
    __syncthreads();
    if (t < 12) {
        float s = 0.f;
        for (int j = 0; j < NCH; j++) s += sb2[j] * fc_w1[j * 12 + t];
        hid[t] = fmaxf(s, 0.f);
    }
    __syncthreads();
    if (t == 0 && n < NCH) {
        float s = 0.f;
        for (int k = 0; k < 12; k++) s += hid[k] * fc_w2[k * NCH + n];
        cgate = 1.f / (1.f + expf(-s));
    }
    __syncthreads();

    // ---- attention: 8 waves = 8 heads ----
    const float scale = 0.125f;
    int w = t >> 6, L = t & 63;   // head, lane
    const float4* kr = (const float4*)(qkv + L * 1536 + INNER + w * DHD);
    const float4* q4 = (const float4*)(sq + w * DHD);
    float s = 0.f;
#pragma unroll
    for (int i = 0; i < 16; i++) {
        float4 kv = kr[i];
        float4 qv = q4[i];
        s += qv.x * kv.x + qv.y * kv.y + qv.z * kv.z + qv.w * kv.w;
    }
    float sL = s * scale;
    float t64 = sq[w * DHD + L] * qkv[64 * 1536 + INNER + w * DHD + L];
#pragma unroll
    for (int off = 1; off < 64; off <<= 1) t64 += __shfl_xor(t64, off, 64);
    float s64 = t64 * scale;
    float mx = sL;
#pragma unroll
    for (int off = 1; off < 64; off <<= 1) mx = fmaxf(mx, __shfl_xor(mx, off, 64));
    mx = fmaxf(mx, s64);
    float e = expf(sL - mx);
    float e64 = expf(s64 - mx);
    float esum = e;
#pragma unroll
    for (int off = 1; off < 64; off <<= 1) esum += __shfl_xor(esum, off, 64);
    esum += e64;
    float rs = 1.f / esum;
    pp[w * 80 + L] = e;
    if (L == 0) pp[w * 80 + 64] = e64;
    __syncthreads();
    float acc = 0.f;
#pragma unroll 13
    for (int m = 0; m < SEQ; m++)
        acc += pp[w * 80 + m] * qkv[m * 1536 + 2 * INNER + w * DHD + L];
    so[w * DHD + L] = acc * rs;
    __syncthreads();

    // ---- out-projection: 98 col-pairs x 4 K-quarters ----
    if (t < 392) {
        int qq = t / 98, p = t - qq * 98;
        const float* wp = w_out + (qq * 128) * D + 2 * p;
        const float* op = so + qq * 128;
        float a0 = 0.f, a1 = 0.f;
#pragma unroll 16
        for (int i = 0; i < 128; i++) {
            float2 w2 = *(const float2*)(wp + i * D);
            float ov = op[i];
            a0 += ov * w2.x;
            a1 += ov * w2.y;
        }
        ps[qq * 196 + 2 * p] = a0;
        ps[qq * 196 + 2 * p + 1] = a1;
    }
    __syncthreads();
    if (t < 98) {
        float s0 = ps[2 * t] + ps[196 + 2 * t] + ps[392 + 2 * t] + ps[588 + 2 * t];
        float s1 = ps[2 * t + 1] + ps[197 + 2 * t] + ps[393 + 2 * t] + ps[589 + 2 * t];
        float2 xr = *(const float2*)(x + n * D + 2 * t);
        float2 br = *(const float2*)(b_out + 2 * t);
        x2row[2 * t] = s0 + xr.x + br.x;
        x2row[2 * t + 1] = s1 + xr.y + br.y;
    }
    __syncthreads();

    // ---- add x_att; seed out with residual + ff_b2 ----
    if (t < D) {
        float att = (n < NCH) ? a[n * D + t] * cgate : tokens[t];
        float xv = x2row[t] + att;
        x2row[t] = xv;
        out[n * D + t] = xv + ff_b2[t];
    }
    __syncthreads();

    // ---- LN2 -> h2g ----
    float v = (t < D) ? x2row[t] : 0.f;
    float mean = bsum8(v, red) * (1.f / (float)D);
    float d = (t < D) ? (v - mean) : 0.f;
    float var = bsum8(d * d, red) * (1.f / (float)D);
    float rinv = rsqrtf(var + 1e-5f);
    if (t < D) h2g[n * D + t] = d * rinv * ln2_g[t] + ln2_b[t];
}

// ===== K3: FF1(98 cols)+GELU+FF2 partial + atomicAdd, grid (65,8) =====
__global__ void __launch_bounds__(256) k3(const float* __restrict__ h2g,
        const float* __restrict__ ff_w1, const float* __restrict__ ff_b1,
        const float* __restrict__ ff_w2, float* __restrict__ out) {
    __shared__ float h2s[D];
    __shared__ float st[98];
    __shared__ float ps[392];
    int n = blockIdx.x, cg = blockIdx.y, t = threadIdx.x;
    if (t < D) h2s[t] = h2g[n * D + t];
    __syncthreads();
    // FF1 splitK4 x colpair over this block's 98 columns
    if (t < D) {
        int qq = t / 49, p = t - qq * 49;    // K quarter, col pair
        int c0 = cg * 98 + 2 * p;
        const float* wp = ff_w1 + (qq * 49) * MLP + c0;
        const float* hp = h2s + qq * 49;
        float a0 = 0.f, a1 = 0.f;
#pragma unroll
        for (int i = 0; i < 49; i++) {
            float2 w2 = *(const float2*)(wp + i * MLP);
            float hv = hp[i];
            a0 += hv * w2.x;
            a1 += hv * w2.y;
        }
        if (qq == 0) { a0 += ff_b1[c0]; a1 += ff_b1[c0 + 1]; }
        ps[qq * 98 + 2 * p] = a0;
        ps[qq * 98 + 2 * p + 1] = a1;
    }
    __syncthreads();
    if (t < 49) {
        float s0 = ps[2 * t] + ps[98 + 2 * t] + ps[196 + 2 * t] + ps[294 + 2 * t];
        float s1 = ps[2 * t + 1] + ps[99 + 2 * t] + ps[197 + 2 * t] + ps[295 + 2 * t];
        st[2 * t] = 0.5f * s0 * (1.f + erff(s0 * 0.70710678118f));
        st[2 * t + 1] = 0.5f * s1 * (1.f + erff(s1 * 0.70710678118f));
    }
    __syncthreads();
    // FF2: st[98] x ff_w2 slice -> partial out row
    if (t < D) {
        int hh = t / 98, p = t - hh * 98;    // K half, col pair
        const float* wp = ff_w2 + (cg * 98 + hh * 49) * D + 2 * p;
        const float* sp = st + hh * 49;
        float a0 = 0.f, a1 = 0.f;
#pragma unroll
        for (int i = 0; i < 49; i++) {
            float2 w2 = *(const float2*)(wp + i * D);
            float sv = sp[i];
            a0 += sv * w2.x;
            a1 += sv * w2.y;
        }
        ps[hh * 196 + 2 * p] = a0;
        ps[hh * 196 + 2 * p + 1] = a1;
    }
    __syncthreads();
    if (t < 98) {
        float s0 = ps[2 * t] + ps[196 + 2 * t];
        float s1 = ps[2 * t + 1] + ps[197 + 2 * t];
        atomicAdd(&out[n * D + 2 * t], s0);
        atomicAdd(&out[n * D + 2 * t + 1], s1);
    }
}

extern "C" void kernel_launch(void* const* d_in, const int* in_sizes, int n_in,
                              void* d_out, int out_size, void* d_ws, size_t ws_size,
                              hipStream_t stream) {
    const float* x      = (const float*)d_in[0];
    const float* tokens = (const float*)d_in[1];
    const float* x_pe   = (const float*)d_in[2];
    const float* conv_k = (const float*)d_in[3];
    const float* bn_g   = (const float*)d_in[4];
    const float* bn_b   = (const float*)d_in[5];
    const float* bn_rm  = (const float*)d_in[6];
    const float* bn_rv  = (const float*)d_in[7];
    const float* fc_w1  = (const float*)d_in[8];
    const float* fc_w2  = (const float*)d_in[9];
    const float* ln1_g  = (const float*)d_in[10];
    const float* ln1_b  = (const float*)d_in[11];
    const float* ln2_g  = (const float*)d_in[12];
    const float* ln2_b  = (const float*)d_in[13];
    const float* w_qkv  = (const float*)d_in[14];
    const float* w_out  = (const float*)d_in[15];
    const float* b_out  = (const float*)d_in[16];
    const float* ff_w1  = (const float*)d_in[17];
    const float* ff_b1  = (const float*)d_in[18];
    const float* ff_w2  = (const float*)d_in[19];
    const float* ff_b2  = (const float*)d_in[20];
    float* out = (float*)d_out;

    float* ws = (float*)d_ws;
    float* a    = ws;             // 12544
    float* b1   = ws + 12544;     // 64
    float* qkv  = ws + 12608;     // 99840
    float* h2g  = ws + 112448;    // 12740

    k1<<<844, 256, 0, stream>>>(x_pe, conv_k, bn_g, bn_b, bn_rm, bn_rv,
                                x, ln1_g, ln1_b, w_qkv, a, b1, qkv);
    k2<<<SEQ, 512, 0, stream>>>(b1, fc_w1, fc_w2, qkv, w_out, b_out, x,
                                a, tokens, ln2_g, ln2_b, ff_b2, h2g, out);
    k3<<<dim3(SEQ, 8), 256, 0, stream>>>(h2g, ff_w1, ff_b1, ff_w2, out);
}

// Round 3
// 130.567 us; speedup vs baseline: 1.2283x; 1.0521x over previous
//
#include <hip/hip_runtime.h>
#include <math.h>

#define D 196
#define NCH 64
#define NH 8
#define DHD 64
#define INNER 512
#define MLP 784
#define SEQ 65

__device__ __forceinline__ float bsum(float v, float* red) {   // 256-thread blocks
    for (int off = 32; off > 0; off >>= 1) v += __shfl_down(v, off, 64);
    int lane = threadIdx.x & 63, wid = threadIdx.x >> 6;
    if (lane == 0) red[wid] = v;
    __syncthreads();
    float s = red[0] + red[1] + red[2] + red[3];
    __syncthreads();
    return s;
}

// ===== K1: conv+mean+zero(out,x2) (blocks 0..63) | LN1+QKV (64..843) =====
__global__ void __launch_bounds__(256) k1(const float* __restrict__ x_pe,
        const float* __restrict__ conv_k, const float* __restrict__ bn_g,
        const float* __restrict__ bn_b, const float* __restrict__ bn_rm,
        const float* __restrict__ bn_rv, const float* __restrict__ x,
        const float* __restrict__ ln1_g, const float* __restrict__ ln1_b,
        const float* __restrict__ w_qkv,
        float* __restrict__ a, float* __restrict__ b1, float* __restrict__ qkv,
        float* __restrict__ out, float* __restrict__ x2g) {
    __shared__ float red[4];
    __shared__ float h[D];
    __shared__ float ps[512];
    int b = blockIdx.x, t = threadIdx.x;
    if (b < NCH) {
        int zi = b * 200 + t;
        if (t < 200 && zi < SEQ * D) { out[zi] = 0.f; x2g[zi] = 0.f; }
        const float* row = x_pe + b * D;
        float val = 0.f;
        if (t < D) {
            float km0 = conv_k[3], km1 = conv_k[4], km2 = conv_k[5];
            float inv = rsqrtf(bn_rv[0] + 1e-5f);
            float l = (t > 0) ? row[t - 1] : 0.f;
            float m = row[t];
            float r = (t < D - 1) ? row[t + 1] : 0.f;
            float conv = km0 * l + km1 * m + km2 * r;
            float bn = (conv - bn_rm[0]) * inv * bn_g[0] + bn_b[0];
            val = fmaxf(bn, 0.f);
            a[b * D + t] = val;
        }
        float tot = bsum(val, red);
        if (t == 0) b1[b] = tot * (1.f / (float)D);
    } else {
        int qb = b - NCH;          // 0..779
        int n = qb / 12, cg = qb % 12;
        const float* row = x + n * D;
        float v = (t < D) ? row[t] : 0.f;
        float mean = bsum(v, red) * (1.f / (float)D);
        float d = (t < D) ? (v - mean) : 0.f;
        float var = bsum(d * d, red) * (1.f / (float)D);
        float rinv = rsqrtf(var + 1e-5f);
        if (t < D) h[t] = d * rinv * ln1_g[t] + ln1_b[t];
        __syncthreads();
        int qq = t >> 6, lt = t & 63;        // qq: K quarter, lt: col pair
        int c0 = cg * 128 + lt * 2;
        const float* wp = w_qkv + (qq * 49) * 1536 + c0;
        const float* hp = h + qq * 49;
        float a0 = 0.f, a1 = 0.f;
#pragma unroll
        for (int i = 0; i < 49; i++) {
            float2 w2 = *(const float2*)(wp + i * 1536);
            float hv = hp[i];
            a0 += hv * w2.x;
            a1 += hv * w2.y;
        }
        ps[qq * 128 + lt * 2] = a0;
        ps[qq * 128 + lt * 2 + 1] = a1;
        __syncthreads();
        if (t < 64) {
            float s0 = ps[t * 2] + ps[128 + t * 2] + ps[256 + t * 2] + ps[384 + t * 2];
            float s1 = ps[t * 2 + 1] + ps[129 + t * 2] + ps[257 + t * 2] + ps[385 + t * 2];
            float2 o2 = make_float2(s0, s1);
            *(float2*)(qkv + n * 1536 + cg * 128 + t * 2) = o2;
        }
    }
}

// ===== K2: attention (4 heads) + splitK out-proj partial, grid (65,2) x 256.
//       g==0 block also computes the gate (wave-0-local) and adds
//       x + b_out + x_att to its partial.  x2 assembled via atomicAdd. =====
__global__ void __launch_bounds__(256) k2(const float* __restrict__ b1,
        const float* __restrict__ fc_w1, const float* __restrict__ fc_w2,
        const float* __restrict__ qkv, const float* __restrict__ w_out,
        const float* __restrict__ b_out, const float* __restrict__ x,
        const float* __restrict__ a, const float* __restrict__ tokens,
        float* __restrict__ x2g) {
    __shared__ float sq[256];      // q for this block's 4 heads
    __shared__ float pp[4 * 80];   // attn probs per head
    __shared__ float so[256];      // attn out (4 x 64)
    __shared__ float ps[784];      // 4 x 196 splitK partials
    __shared__ float sb1[NCH];
    __shared__ float sb2[NCH];
    __shared__ float hid[12];
    __shared__ float cgate;

    int n = blockIdx.x, g = blockIdx.y, t = threadIdx.x;
    int w = t >> 6, L = t & 63, head = g * 4 + w;

    sq[t] = qkv[n * 1536 + g * 256 + t];

    // ---- gate: entirely within wave 0 of g==0 blocks, no barriers ----
    if (g == 0) {
        if (t < NCH) {
            sb1[t] = b1[t];
            float v = b1[t];
            float mx = -1e30f, mn = 1e30f;
            int cle = 0, rank = 0;
            for (int j = 0; j < NCH; j++) {
                float ww = sb1[j];
                mx = fmaxf(mx, ww);
                mn = fminf(mn, ww);
                if (ww <= 0.f) cle++;
                if (ww < v || (ww == v && j < t)) rank++;
            }
            int middle;
            if (mx < 0.f || mn > 0.f) middle = 32;
            else if (mx <= 0.f) middle = 0;
            else middle = cle;
            float b2;
            if (rank < middle) {
                float ls = (float)middle;
                b2 = v - 1.f / (1.f + powf(ls, v));
            } else {
                float le = (float)(NCH - middle);
                b2 = v + 1.f / (1.f + powf(le, -v));
            }
            sb2[t] = b2;
        }
        if (t < 12) {
            float s = 0.f;
            for (int j = 0; j < NCH; j++) s += sb2[j] * fc_w1[j * 12 + t];
            hid[t] = fmaxf(s, 0.f);
        }
        if (t == 0 && n < NCH) {
            float s = 0.f;
            for (int k = 0; k < 12; k++) s += hid[k] * fc_w2[k * NCH + n];
            cgate = 1.f / (1.f + expf(-s));
        }
    }

    // ---- attention (all same-wave LDS; no barriers needed) ----
    const float scale = 0.125f;
    const float4* kr = (const float4*)(qkv + L * 1536 + INNER + head * DHD);
    const float4* q4 = (const float4*)(sq + w * DHD);
    float s = 0.f;
#pragma unroll
    for (int i = 0; i < 16; i++) {
        float4 kv = kr[i];
        float4 qv = q4[i];
        s += qv.x * kv.x + qv.y * kv.y + qv.z * kv.z + qv.w * kv.w;
    }
    float sL = s * scale;
    float t64 = sq[w * DHD + L] * qkv[64 * 1536 + INNER + head * DHD + L];
#pragma unroll
    for (int off = 1; off < 64; off <<= 1) t64 += __shfl_xor(t64, off, 64);
    float s64 = t64 * scale;
    float mx = sL;
#pragma unroll
    for (int off = 1; off < 64; off <<= 1) mx = fmaxf(mx, __shfl_xor(mx, off, 64));
    mx = fmaxf(mx, s64);
    float e = expf(sL - mx);
    float e64 = expf(s64 - mx);
    float esum = e;
#pragma unroll
    for (int off = 1; off < 64; off <<= 1) esum += __shfl_xor(esum, off, 64);
    esum += e64;
    float rs = 1.f / esum;
    pp[w * 80 + L] = e;
    if (L == 0) pp[w * 80 + 64] = e64;
    float acc = 0.f;
#pragma unroll 13
    for (int m = 0; m < SEQ; m++)
        acc += pp[w * 80 + m] * qkv[m * 1536 + 2 * INNER + head * DHD + L];
    so[w * DHD + L] = acc * rs;
    __syncthreads();

    // ---- out-proj partial: K = this block's 256 dims; float4 over col-quads ----
    if (t < 196) {
        int qq = t / 49, quad = t - qq * 49;
        const float* wp = w_out + (g * 256 + qq * 64) * D + 4 * quad;
        const float* op = so + qq * 64;
        float a0 = 0.f, a1 = 0.f, a2 = 0.f, a3 = 0.f;
#pragma unroll 16
        for (int i = 0; i < 64; i++) {
            float4 w4 = *(const float4*)(wp + i * D);
            float ov = op[i];
            a0 += ov * w4.x;
            a1 += ov * w4.y;
            a2 += ov * w4.z;
            a3 += ov * w4.w;
        }
        ps[qq * 196 + 4 * quad]     = a0;
        ps[qq * 196 + 4 * quad + 1] = a1;
        ps[qq * 196 + 4 * quad + 2] = a2;
        ps[qq * 196 + 4 * quad + 3] = a3;
    }
    __syncthreads();
    if (t < 196) {
        float sacc = ps[t] + ps[196 + t] + ps[392 + t] + ps[588 + t];
        if (g == 0) {
            float att = (n < NCH) ? a[n * D + t] * cgate : tokens[t];
            sacc += x[n * D + t] + b_out[t] + att;
        }
        atomicAdd(&x2g[n * D + t], sacc);
    }
}

// ===== K3: LN2 (redundant) + FF1+GELU+FF2 partial + atomicAdd, grid (65,8) =====
__global__ void __launch_bounds__(256) k3(const float* __restrict__ x2g,
        const float* __restrict__ ln2_g, const float* __restrict__ ln2_b,
        const float* __restrict__ ff_w1, const float* __restrict__ ff_b1,
        const float* __restrict__ ff_w2, const float* __restrict__ ff_b2,
        float* __restrict__ out) {
    __shared__ float red[4];
    __shared__ float x2s[D];
    __shared__ float h2s[D];
    __shared__ float st[98];
    __shared__ float ps[392];
    int n = blockIdx.x, cg = blockIdx.y, t = threadIdx.x;
    float v = 0.f;
    if (t < D) { v = x2g[n * D + t]; x2s[t] = v; }
    float mean = bsum(v, red) * (1.f / (float)D);
    float d = (t < D) ? (v - mean) : 0.f;
    float var = bsum(d * d, red) * (1.f / (float)D);
    float rinv = rsqrtf(var + 1e-5f);
    if (t < D) h2s[t] = d * rinv * ln2_g[t] + ln2_b[t];
    __syncthreads();
    // FF1 splitK4 x colpair over this block's 98 columns
    if (t < D) {
        int qq = t / 49, p = t - qq * 49;    // K quarter, col pair
        int c0 = cg * 98 + 2 * p;
        const float* wp = ff_w1 + (qq * 49) * MLP + c0;
        const float* hp = h2s + qq * 49;
        float a0 = 0.f, a1 = 0.f;
#pragma unroll
        for (int i = 0; i < 49; i++) {
            float2 w2 = *(const float2*)(wp + i * MLP);
            float hv = hp[i];
            a0 += hv * w2.x;
            a1 += hv * w2.y;
        }
        if (qq == 0) { a0 += ff_b1[c0]; a1 += ff_b1[c0 + 1]; }
        ps[qq * 98 + 2 * p] = a0;
        ps[qq * 98 + 2 * p + 1] = a1;
    }
    __syncthreads();
    if (t < 49) {
        float s0 = ps[2 * t] + ps[98 + 2 * t] + ps[196 + 2 * t] + ps[294 + 2 * t];
        float s1 = ps[2 * t + 1] + ps[99 + 2 * t] + ps[197 + 2 * t] + ps[295 + 2 * t];
        st[2 * t] = 0.5f * s0 * (1.f + erff(s0 * 0.70710678118f));
        st[2 * t + 1] = 0.5f * s1 * (1.f + erff(s1 * 0.70710678118f));
    }
    __syncthreads();
    // FF2: st[98] x ff_w2 slice -> partial out row
    if (t < D) {
        int hh = t / 98, p = t - hh * 98;    // K half, col pair
        const float* wp = ff_w2 + (cg * 98 + hh * 49) * D + 2 * p;
        const float* sp = st + hh * 49;
        float a0 = 0.f, a1 = 0.f;
#pragma unroll
        for (int i = 0; i < 49; i++) {
            float2 w2 = *(const float2*)(wp + i * D);
            float sv = sp[i];
            a0 += sv * w2.x;
            a1 += sv * w2.y;
        }
        ps[hh * 196 + 2 * p] = a0;
        ps[hh * 196 + 2 * p + 1] = a1;
    }
    __syncthreads();
    if (t < 98) {
        float s0 = ps[2 * t] + ps[196 + 2 * t];
        float s1 = ps[2 * t + 1] + ps[197 + 2 * t];
        if (cg == 0) {
            s0 += ff_b2[2 * t] + x2s[2 * t];
            s1 += ff_b2[2 * t + 1] + x2s[2 * t + 1];
        }
        atomicAdd(&out[n * D + 2 * t], s0);
        atomicAdd(&out[n * D + 2 * t + 1], s1);
    }
}

extern "C" void kernel_launch(void* const* d_in, const int* in_sizes, int n_in,
                              void* d_out, int out_size, void* d_ws, size_t ws_size,
                              hipStream_t stream) {
    const float* x      = (const float*)d_in[0];
    const float* tokens = (const float*)d_in[1];
    const float* x_pe   = (const float*)d_in[2];
    const float* conv_k = (const float*)d_in[3];
    const float* bn_g   = (const float*)d_in[4];
    const float* bn_b   = (const float*)d_in[5];
    const float* bn_rm  = (const float*)d_in[6];
    const float* bn_rv  = (const float*)d_in[7];
    const float* fc_w1  = (const float*)d_in[8];
    const float* fc_w2  = (const float*)d_in[9];
    const float* ln1_g  = (const float*)d_in[10];
    const float* ln1_b  = (const float*)d_in[11];
    const float* ln2_g  = (const float*)d_in[12];
    const float* ln2_b  = (const float*)d_in[13];
    const float* w_qkv  = (const float*)d_in[14];
    const float* w_out  = (const float*)d_in[15];
    const float* b_out  = (const float*)d_in[16];
    const float* ff_w1  = (const float*)d_in[17];
    const float* ff_b1  = (const float*)d_in[18];
    const float* ff_w2  = (const float*)d_in[19];
    const float* ff_b2  = (const float*)d_in[20];
    float* out = (float*)d_out;

    float* ws = (float*)d_ws;
    float* a    = ws;             // 12544
    float* b1   = ws + 12544;     // 64
    float* qkv  = ws + 12608;     // 99840
    float* x2g  = ws + 112448;    // 12740

    k1<<<844, 256, 0, stream>>>(x_pe, conv_k, bn_g, bn_b, bn_rm, bn_rv,
                                x, ln1_g, ln1_b, w_qkv, a, b1, qkv, out, x2g);
    k2<<<dim3(SEQ, 2), 256, 0, stream>>>(b1, fc_w1, fc_w2, qkv, w_out, b_out,
                                         x, a, tokens, x2g);
    k3<<<dim3(SEQ, 8), 256, 0, stream>>>(x2g, ln2_g, ln2_b,
                                         ff_w1, ff_b1, ff_w2, ff_b2, out);
}

// Round 4
// 126.735 us; speedup vs baseline: 1.2654x; 1.0302x over previous
//
#include <hip/hip_runtime.h>
#include <math.h>

#define D 196
#define NCH 64
#define NH 8
#define DHD 64
#define INNER 512
#define MLP 784
#define SEQ 65

__device__ __forceinline__ float bsum(float v, float* red) {   // 256-thread blocks
    for (int off = 32; off > 0; off >>= 1) v += __shfl_down(v, off, 64);
    int lane = threadIdx.x & 63, wid = threadIdx.x >> 6;
    if (lane == 0) red[wid] = v;
    __syncthreads();
    float s = red[0] + red[1] + red[2] + red[3];
    __syncthreads();
    return s;
}

// ===== K1: conv+mean+zero(out,x2) (blocks 0..63) | LN1+QKV (64..843) =====
__global__ void __launch_bounds__(256) k1(const float* __restrict__ x_pe,
        const float* __restrict__ conv_k, const float* __restrict__ bn_g,
        const float* __restrict__ bn_b, const float* __restrict__ bn_rm,
        const float* __restrict__ bn_rv, const float* __restrict__ x,
        const float* __restrict__ ln1_g, const float* __restrict__ ln1_b,
        const float* __restrict__ w_qkv,
        float* __restrict__ a, float* __restrict__ b1, float* __restrict__ qkv,
        float* __restrict__ out, float* __restrict__ x2g) {
    __shared__ float red[4];
    __shared__ float h[D];
    __shared__ float ps[512];
    int b = blockIdx.x, t = threadIdx.x;
    if (b < NCH) {
        int zi = b * 200 + t;
        if (t < 200 && zi < SEQ * D) { out[zi] = 0.f; x2g[zi] = 0.f; }
        const float* row = x_pe + b * D;
        float val = 0.f;
        if (t < D) {
            float km0 = conv_k[3], km1 = conv_k[4], km2 = conv_k[5];
            float inv = rsqrtf(bn_rv[0] + 1e-5f);
            float l = (t > 0) ? row[t - 1] : 0.f;
            float m = row[t];
            float r = (t < D - 1) ? row[t + 1] : 0.f;
            float conv = km0 * l + km1 * m + km2 * r;
            float bn = (conv - bn_rm[0]) * inv * bn_g[0] + bn_b[0];
            val = fmaxf(bn, 0.f);
            a[b * D + t] = val;
        }
        float tot = bsum(val, red);
        if (t == 0) b1[b] = tot * (1.f / (float)D);
    } else {
        int qb = b - NCH;          // 0..779
        int n = qb / 12, cg = qb % 12;
        const float* row = x + n * D;
        float v = (t < D) ? row[t] : 0.f;
        float mean = bsum(v, red) * (1.f / (float)D);
        float d = (t < D) ? (v - mean) : 0.f;
        float var = bsum(d * d, red) * (1.f / (float)D);
        float rinv = rsqrtf(var + 1e-5f);
        if (t < D) h[t] = d * rinv * ln1_g[t] + ln1_b[t];
        __syncthreads();
        int qq = t >> 6, lt = t & 63;        // qq: K quarter, lt: col pair
        int c0 = cg * 128 + lt * 2;
        const float* wp = w_qkv + (qq * 49) * 1536 + c0;
        const float* hp = h + qq * 49;
        float a0 = 0.f, a1 = 0.f;
#pragma unroll
        for (int i = 0; i < 49; i++) {
            float2 w2 = *(const float2*)(wp + i * 1536);
            float hv = hp[i];
            a0 += hv * w2.x;
            a1 += hv * w2.y;
        }
        ps[qq * 128 + lt * 2] = a0;
        ps[qq * 128 + lt * 2 + 1] = a1;
        __syncthreads();
        if (t < 64) {
            float s0 = ps[t * 2] + ps[128 + t * 2] + ps[256 + t * 2] + ps[384 + t * 2];
            float s1 = ps[t * 2 + 1] + ps[129 + t * 2] + ps[257 + t * 2] + ps[385 + t * 2];
            float2 o2 = make_float2(s0, s1);
            *(float2*)(qkv + n * 1536 + cg * 128 + t * 2) = o2;
        }
    }
}

// ===== K2: attention (2 heads) + splitK out-proj partial, grid (65,4) x 256.
//       g==0 block also computes the gate (wave-0-local) and adds
//       x + b_out + x_att to its partial.  x2 assembled via atomicAdd. =====
__global__ void __launch_bounds__(256) k2(const float* __restrict__ b1,
        const float* __restrict__ fc_w1, const float* __restrict__ fc_w2,
        const float* __restrict__ qkv, const float* __restrict__ w_out,
        const float* __restrict__ b_out, const float* __restrict__ x,
        const float* __restrict__ a, const float* __restrict__ tokens,
        float* __restrict__ x2g) {
    __shared__ float sq[128];      // q for this block's 2 heads
    __shared__ float pp[2 * 80];   // attn probs per head
    __shared__ float so[128];      // attn out (2 x 64)
    __shared__ float ps[784];      // 4 x 196 splitK partials
    __shared__ float sb1[NCH];
    __shared__ float sb2[NCH];
    __shared__ float hid[12];
    __shared__ float cgate;

    int n = blockIdx.x, g = blockIdx.y, t = threadIdx.x;
    int w = t >> 6, L = t & 63;

    if (t < 128) sq[t] = qkv[n * 1536 + g * 128 + t];

    // ---- gate: entirely within wave 0 of g==0 blocks, no barriers ----
    if (g == 0) {
        if (t < NCH) {
            sb1[t] = b1[t];
            float v = b1[t];
            float mx = -1e30f, mn = 1e30f;
            int cle = 0, rank = 0;
            for (int j = 0; j < NCH; j++) {
                float ww = sb1[j];
                mx = fmaxf(mx, ww);
                mn = fminf(mn, ww);
                if (ww <= 0.f) cle++;
                if (ww < v || (ww == v && j < t)) rank++;
            }
            int middle;
            if (mx < 0.f || mn > 0.f) middle = 32;
            else if (mx <= 0.f) middle = 0;
            else middle = cle;
            float b2;
            if (rank < middle) {
                float ls = (float)middle;
                b2 = v - 1.f / (1.f + powf(ls, v));
            } else {
                float le = (float)(NCH - middle);
                b2 = v + 1.f / (1.f + powf(le, -v));
            }
            sb2[t] = b2;
        }
        if (t < 12) {
            float s = 0.f;
            for (int j = 0; j < NCH; j++) s += sb2[j] * fc_w1[j * 12 + t];
            hid[t] = fmaxf(s, 0.f);
        }
        if (t == 0 && n < NCH) {
            float s = 0.f;
            for (int k = 0; k < 12; k++) s += hid[k] * fc_w2[k * NCH + n];
            cgate = 1.f / (1.f + expf(-s));
        }
    }

    // ---- attention: waves 0,1 = this block's 2 heads (same-wave LDS, no barriers)
    if (t < 128) {
        int head = g * 2 + w;
        const float scale = 0.125f;
        const float4* kr = (const float4*)(qkv + L * 1536 + INNER + head * DHD);
        const float4* q4 = (const float4*)(sq + w * DHD);
        float s = 0.f;
#pragma unroll
        for (int i = 0; i < 16; i++) {
            float4 kv = kr[i];
            float4 qv = q4[i];
            s += qv.x * kv.x + qv.y * kv.y + qv.z * kv.z + qv.w * kv.w;
        }
        float sL = s * scale;
        float t64 = sq[w * DHD + L] * qkv[64 * 1536 + INNER + head * DHD + L];
#pragma unroll
        for (int off = 1; off < 64; off <<= 1) t64 += __shfl_xor(t64, off, 64);
        float s64 = t64 * scale;
        float mx = sL;
#pragma unroll
        for (int off = 1; off < 64; off <<= 1) mx = fmaxf(mx, __shfl_xor(mx, off, 64));
        mx = fmaxf(mx, s64);
        float e = expf(sL - mx);
        float e64 = expf(s64 - mx);
        float esum = e;
#pragma unroll
        for (int off = 1; off < 64; off <<= 1) esum += __shfl_xor(esum, off, 64);
        esum += e64;
        float rs = 1.f / esum;
        pp[w * 80 + L] = e;
        if (L == 0) pp[w * 80 + 64] = e64;
        float acc = 0.f;
#pragma unroll 13
        for (int m = 0; m < SEQ; m++)
            acc += pp[w * 80 + m] * qkv[m * 1536 + 2 * INNER + head * DHD + L];
        so[w * DHD + L] = acc * rs;
    }
    __syncthreads();

    // ---- out-proj partial: K = this block's 128 dims, splitK4 x col-quads ----
    if (t < 196) {
        int qq = t / 49, p = t - qq * 49;
        const float* wp = w_out + (g * 128 + qq * 32) * D + 4 * p;
        const float* op = so + qq * 32;
        float a0 = 0.f, a1 = 0.f, a2 = 0.f, a3 = 0.f;
#pragma unroll
        for (int i = 0; i < 32; i++) {
            float4 w4 = *(const float4*)(wp + i * D);
            float ov = op[i];
            a0 += ov * w4.x;
            a1 += ov * w4.y;
            a2 += ov * w4.z;
            a3 += ov * w4.w;
        }
        ps[qq * 196 + 4 * p]     = a0;
        ps[qq * 196 + 4 * p + 1] = a1;
        ps[qq * 196 + 4 * p + 2] = a2;
        ps[qq * 196 + 4 * p + 3] = a3;
    }
    __syncthreads();
    if (t < 196) {
        float sacc = ps[t] + ps[196 + t] + ps[392 + t] + ps[588 + t];
        if (g == 0) {
            float att = (n < NCH) ? a[n * D + t] * cgate : tokens[t];
            sacc += x[n * D + t] + b_out[t] + att;
        }
        atomicAdd(&x2g[n * D + t], sacc);
    }
}

// ===== K3: LN2 (redundant) + FF1(49 cols)+GELU+FF2 column-dots + atomicAdd,
//       grid (65,16) x 256 =====
__global__ void __launch_bounds__(256) k3(const float* __restrict__ x2g,
        const float* __restrict__ ln2_g, const float* __restrict__ ln2_b,
        const float* __restrict__ ff_w1, const float* __restrict__ ff_b1,
        const float* __restrict__ ff_w2, const float* __restrict__ ff_b2,
        float* __restrict__ out) {
    __shared__ float red[4];
    __shared__ float x2s[D];
    __shared__ float h2s[D];
    __shared__ float st[49];
    __shared__ float ps[196];
    int n = blockIdx.x, cg = blockIdx.y, t = threadIdx.x;   // cg 0..15
    float v = 0.f;
    if (t < D) { v = x2g[n * D + t]; x2s[t] = v; }
    float mean = bsum(v, red) * (1.f / (float)D);
    float d = (t < D) ? (v - mean) : 0.f;
    float var = bsum(d * d, red) * (1.f / (float)D);
    float rinv = rsqrtf(var + 1e-5f);
    if (t < D) h2s[t] = d * rinv * ln2_g[t] + ln2_b[t];
    __syncthreads();
    // FF1 splitK4 over this block's 49 columns
    if (t < 196) {
        int qq = t / 49, p = t - qq * 49;    // K quarter, column
        int c0 = cg * 49 + p;
        const float* wp = ff_w1 + (qq * 49) * MLP + c0;
        const float* hp = h2s + qq * 49;
        float a0 = 0.f;
#pragma unroll
        for (int i = 0; i < 49; i++) a0 += hp[i] * wp[i * MLP];
        ps[qq * 49 + p] = a0;
    }
    __syncthreads();
    if (t < 49) {
        float s0 = ps[t] + ps[49 + t] + ps[98 + t] + ps[147 + t] + ff_b1[cg * 49 + t];
        st[t] = 0.5f * s0 * (1.f + erff(s0 * 0.70710678118f));
    }
    __syncthreads();
    // FF2: each thread owns one output column over this block's 49 K rows
    if (t < D) {
        const float* wp = ff_w2 + (cg * 49) * D + t;
        float s = 0.f;
#pragma unroll
        for (int i = 0; i < 49; i++) s += st[i] * wp[i * D];
        if (cg == 0) s += ff_b2[t] + x2s[t];
        atomicAdd(&out[n * D + t], s);
    }
}

extern "C" void kernel_launch(void* const* d_in, const int* in_sizes, int n_in,
                              void* d_out, int out_size, void* d_ws, size_t ws_size,
                              hipStream_t stream) {
    const float* x      = (const float*)d_in[0];
    const float* tokens = (const float*)d_in[1];
    const float* x_pe   = (const float*)d_in[2];
    const float* conv_k = (const float*)d_in[3];
    const float* bn_g   = (const float*)d_in[4];
    const float* bn_b   = (const float*)d_in[5];
    const float* bn_rm  = (const float*)d_in[6];
    const float* bn_rv  = (const float*)d_in[7];
    const float* fc_w1  = (const float*)d_in[8];
    const float* fc_w2  = (const float*)d_in[9];
    const float* ln1_g  = (const float*)d_in[10];
    const float* ln1_b  = (const float*)d_in[11];
    const float* ln2_g  = (const float*)d_in[12];
    const float* ln2_b  = (const float*)d_in[13];
    const float* w_qkv  = (const float*)d_in[14];
    const float* w_out  = (const float*)d_in[15];
    const float* b_out  = (const float*)d_in[16];
    const float* ff_w1  = (const float*)d_in[17];
    const float* ff_b1  = (const float*)d_in[18];
    const float* ff_w2  = (const float*)d_in[19];
    const float* ff_b2  = (const float*)d_in[20];
    float* out = (float*)d_out;

    float* ws = (float*)d_ws;
    float* a    = ws;             // 12544
    float* b1   = ws + 12544;     // 64
    float* qkv  = ws + 12608;     // 99840
    float* x2g  = ws + 112448;    // 12740

    k1<<<844, 256, 0, stream>>>(x_pe, conv_k, bn_g, bn_b, bn_rm, bn_rv,
                                x, ln1_g, ln1_b, w_qkv, a, b1, qkv, out, x2g);
    k2<<<dim3(SEQ, 4), 256, 0, stream>>>(b1, fc_w1, fc_w2, qkv, w_out, b_out,
                                         x, a, tokens, x2g);
    k3<<<dim3(SEQ, 16), 256, 0, stream>>>(x2g, ln2_g, ln2_b,
                                          ff_w1, ff_b1, ff_w2, ff_b2, out);
}